// Round 5
// baseline (3354.125 us; speedup 1.0000x reference)
//
#include <hip/hip_runtime.h>
#include <hip/hip_bf16.h>

typedef unsigned int u32;
typedef unsigned short u16;

#define BB 512
#define NN 256
#define DD 128
#define SCALE 0.08838834764831845f

__device__ __forceinline__ float bf2f(u16 u) {
  union { u32 i; float f; } v; v.i = ((u32)u) << 16; return v.f;
}
__device__ __forceinline__ u16 f2bf(float f) {
  union { u32 i; float f; } v; v.f = f;
  u32 i = v.i;
  u32 rounded = i + 0x7FFFu + ((i >> 16) & 1u);
  return (u16)(rounded >> 16);
}
__device__ __forceinline__ u32 pack2(float a, float b) {
  return (u32)f2bf(a) | ((u32)f2bf(b) << 16);
}

// ---------------- K0: M1T/M2T = Wq^T Wk  (stored as M[dp*128+d] = M?[d][dp]) ----
__global__ void k_prep(const float* __restrict__ Wq1, const float* __restrict__ Wk1,
                       const float* __restrict__ Wq2, const float* __restrict__ Wk2,
                       float* __restrict__ M) {
  int dp = blockIdx.x & 127;
  bool first = blockIdx.x < 128;
  const float* Wq = first ? Wq1 : Wq2;
  const float* Wk = first ? Wk1 : Wk2;
  float* out = M + (first ? 0 : 16384);
  int d = threadIdx.x;
  float acc = 0.f;
  for (int e = 0; e < 128; ++e)
    acc += Wq[e * 128 + d] * Wk[e * 128 + dp];
  out[dp * 128 + d] = acc;  // M?[d][dp]
}

// ---------------- K1: stage 1 (alpha, sat_out) + k2 projection -------------------
// out0 <- sat_out (fp32). out1 <- k2 = M2 @ sat_out (fp32, staged; overwritten by k_attn)
__global__ __launch_bounds__(512) void k_stage1(
    const float* __restrict__ mir, const float* __restrict__ sat,
    const float* __restrict__ M, float* __restrict__ out0, float* __restrict__ out1) {
  extern __shared__ char smem[];
  u16* m1b = (u16*)smem;               // [128][128] bf16: m1b[dp*128+d] = M1[d][dp]
  u16* m2b = m1b + 16384;              // [128][128]
  float* mirS = (float*)(m2b + 16384); // [16][128]
  int tid = threadIdx.x;
  for (int idx = tid; idx < 16384; idx += 512) {
    m1b[idx] = f2bf(M[idx]);
    m2b[idx] = f2bf(M[16384 + idx]);
  }
  int lane = tid & 63;
  int w = tid >> 6;          // 8 waves
  int n0 = w, n1 = w + 8;    // local node ids within the 16-node tile
  size_t base = (size_t)blockIdx.x * 256;
  const u32* m1w = (const u32*)m1b;
  const u32* m2w = (const u32*)m2b;
  for (int it = 0; it < 16; ++it) {
    size_t nb = base + (size_t)it * 16;
    __syncthreads();
    for (int idx = tid; idx < 2048; idx += 512)
      mirS[idx] = mir[nb * 128 + idx];
    __syncthreads();
    // t1[n][d] = sum_dp M1[d,dp] * mir[n,dp]; thread owns d = 2*lane, 2*lane+1
    float a00 = 0.f, a01 = 0.f, a10 = 0.f, a11 = 0.f;
    for (int dp = 0; dp < 128; ++dp) {
      u32 mu = m1w[dp * 64 + lane];              // conflict-free: consecutive words
      float mv0 = bf2f((u16)mu), mv1 = bf2f((u16)(mu >> 16));
      float x0 = mirS[n0 * 128 + dp];            // broadcast
      float x1 = mirS[n1 * 128 + dp];
      a00 += mv0 * x0; a01 += mv1 * x0;
      a10 += mv0 * x1; a11 += mv1 * x1;
    }
    float2 sg0 = *(const float2*)(sat + (nb + n0) * 128 + 2 * lane);
    float2 sg1 = *(const float2*)(sat + (nb + n1) * 128 + 2 * lane);
    float p0 = sg0.x * a00 + sg0.y * a01;
    float p1 = sg1.x * a10 + sg1.y * a11;
    for (int o = 32; o; o >>= 1) {
      p0 += __shfl_xor(p0, o, 64);
      p1 += __shfl_xor(p1, o, 64);
    }
    float al0 = p0 * SCALE, al1 = p1 * SCALE;
    float mg0x = mirS[n0 * 128 + 2 * lane], mg0y = mirS[n0 * 128 + 2 * lane + 1];
    float mg1x = mirS[n1 * 128 + 2 * lane], mg1y = mirS[n1 * 128 + 2 * lane + 1];
    float so00 = sg0.x + al0 * (mg0x - sg0.x), so01 = sg0.y + al0 * (mg0y - sg0.y);
    float so10 = sg1.x + al1 * (mg1x - sg1.x), so11 = sg1.y + al1 * (mg1y - sg1.y);
    ((float2*)out0)[(nb + n0) * 64 + lane] = make_float2(so00, so01);
    ((float2*)out0)[(nb + n1) * 64 + lane] = make_float2(so10, so11);
    // k2[n][d] = sum_dp M2[d,dp] * so[n][dp]; so[n][dp] lives in lane dp/2's regs
    float b00 = 0.f, b01 = 0.f, b10 = 0.f, b11 = 0.f;
    for (int dph = 0; dph < 64; ++dph) {
      float xA0 = __shfl(so00, dph, 64);  // so[n0][2*dph]
      float xB0 = __shfl(so01, dph, 64);  // so[n0][2*dph+1]
      float xA1 = __shfl(so10, dph, 64);
      float xB1 = __shfl(so11, dph, 64);
      u32 muA = m2w[(2 * dph) * 64 + lane];
      u32 muB = m2w[(2 * dph + 1) * 64 + lane];
      float mA0 = bf2f((u16)muA), mA1 = bf2f((u16)(muA >> 16));
      float mB0 = bf2f((u16)muB), mB1 = bf2f((u16)(muB >> 16));
      b00 += mA0 * xA0 + mB0 * xB0;
      b01 += mA1 * xA0 + mB1 * xB0;
      b10 += mA0 * xA1 + mB0 * xB1;
      b11 += mA1 * xA1 + mB1 * xB1;
    }
    ((float2*)out1)[(nb + n0) * 64 + lane] = make_float2(b00, b01);
    ((float2*)out1)[(nb + n1) * 64 + lane] = make_float2(b10, b11);
  }
}

// ---------------- K2: per-batch attention: beta = softmax(mir @ k2^T), out = beta@mir
#define LSTR 130  // LDS row stride in bf16 elements; word-stride 65 (odd) -> conflict-free
__global__ __launch_bounds__(512) void k_attn(
    const float* __restrict__ mir, const int* __restrict__ mask,
    float* __restrict__ out1) {
  extern __shared__ char smem[];
  u16* k2S = (u16*)smem;                   // [256][130]
  u16* mirS = k2S + 256 * LSTR;            // [256][130]
  int* maskS = (int*)(mirS + 256 * LSTR);  // [256]
  int b = blockIdx.x;
  int tid = threadIdx.x;
  const float2* k2in = (const float2*)(out1 + (size_t)b * 32768);
  const float2* mirb = (const float2*)(mir + (size_t)b * 32768);
  for (int idx = tid; idx < 16384; idx += 512) {
    int j = idx >> 6, c = idx & 63;  // c = d/2
    float2 kf = k2in[idx];
    ((u32*)k2S)[j * 65 + c] = pack2(kf.x, kf.y);
    float2 f = mirb[idx];
    ((u32*)mirS)[j * 65 + c] = pack2(f.x, f.y);
  }
  if (tid < 256) maskS[tid] = mask[b * 256 + tid];
  __syncthreads();
  int w = tid >> 6, lane = tid & 63;
  for (int k = 0; k < 16; ++k) {
    int i0 = w + 8 * k, i1 = i0 + 128;
    float s0[4] = {0.f, 0.f, 0.f, 0.f}, s1[4] = {0.f, 0.f, 0.f, 0.f};
    const u16* q0p = mirS + i0 * LSTR;
    const u16* q1p = mirS + i1 * LSTR;
    for (int dp = 0; dp < 128; dp += 2) {
      u32 q0u = *(const u32*)(q0p + dp);
      u32 q1u = *(const u32*)(q1p + dp);
      float q00 = bf2f((u16)q0u), q01 = bf2f((u16)(q0u >> 16));
      float q10 = bf2f((u16)q1u), q11 = bf2f((u16)(q1u >> 16));
#pragma unroll
      for (int jj = 0; jj < 4; ++jj) {
        int j = lane + 64 * jj;
        u32 ku = *(const u32*)(k2S + j * LSTR + dp);
        float k0 = bf2f((u16)ku), k1v = bf2f((u16)(ku >> 16));
        s0[jj] += q00 * k0; s0[jj] += q01 * k1v;
        s1[jj] += q10 * k0; s1[jj] += q11 * k1v;
      }
    }
    float m0 = -1e30f, m1v = -1e30f;
#pragma unroll
    for (int jj = 0; jj < 4; ++jj) {
      int j = lane + 64 * jj;
      bool valid = maskS[j] != 0;
      s0[jj] = valid ? s0[jj] * SCALE : -1e30f;
      s1[jj] = valid ? s1[jj] * SCALE : -1e30f;
      m0 = fmaxf(m0, s0[jj]); m1v = fmaxf(m1v, s1[jj]);
    }
    for (int o = 32; o; o >>= 1) {
      m0 = fmaxf(m0, __shfl_xor(m0, o, 64));
      m1v = fmaxf(m1v, __shfl_xor(m1v, o, 64));
    }
    float l0 = 0.f, l1 = 0.f;
#pragma unroll
    for (int jj = 0; jj < 4; ++jj) {
      s0[jj] = __expf(s0[jj] - m0); l0 += s0[jj];
      s1[jj] = __expf(s1[jj] - m1v); l1 += s1[jj];
    }
    for (int o = 32; o; o >>= 1) {
      l0 += __shfl_xor(l0, o, 64);
      l1 += __shfl_xor(l1, o, 64);
    }
    float inv0 = 1.f / l0, inv1 = 1.f / l1;
    float o00 = 0.f, o01 = 0.f, o10 = 0.f, o11 = 0.f;
#pragma unroll
    for (int jj = 0; jj < 4; ++jj) {
      float ps0 = s0[jj], ps1 = s1[jj];
      for (int jr = 0; jr < 64; ++jr) {
        int j = jj * 64 + jr;
        float p0 = __shfl(ps0, jr, 64);
        float p1 = __shfl(ps1, jr, 64);
        u32 u = *(const u32*)(mirS + j * LSTR + 2 * lane);
        float v0 = bf2f((u16)u), v1 = bf2f((u16)(u >> 16));
        o00 += p0 * v0; o01 += p0 * v1;
        o10 += p1 * v0; o11 += p1 * v1;
      }
    }
    ((float2*)out1)[((size_t)b * 256 + i0) * 64 + lane] = make_float2(o00 * inv0, o01 * inv0);
    ((float2*)out1)[((size_t)b * 256 + i1) * 64 + lane] = make_float2(o10 * inv1, o11 * inv1);
  }
}

extern "C" void kernel_launch(void* const* d_in, const int* in_sizes, int n_in,
                              void* d_out, int out_size, void* d_ws, size_t ws_size,
                              hipStream_t stream) {
  const float* mir = (const float*)d_in[0];
  const float* sat = (const float*)d_in[1];
  const int* mask = (const int*)d_in[2];
  const float* Wq1 = (const float*)d_in[3];
  const float* Wk1 = (const float*)d_in[4];
  const float* Wq2 = (const float*)d_in[5];
  const float* Wk2 = (const float*)d_in[6];
  float* out0 = (float*)d_out;
  float* out1 = out0 + (size_t)BB * NN * DD;
  float* M = (float*)d_ws;  // M1T (16384 floats) then M2T (16384 floats)

  hipFuncSetAttribute((const void*)k_stage1, hipFuncAttributeMaxDynamicSharedMemorySize, 73728);
  hipFuncSetAttribute((const void*)k_attn, hipFuncAttributeMaxDynamicSharedMemorySize, 134144);

  k_prep<<<256, 128, 0, stream>>>(Wq1, Wk1, Wq2, Wk2, M);
  k_stage1<<<512, 512, 73728, stream>>>(mir, sat, M, out0, out1);
  k_attn<<<512, 512, 134144, stream>>>(mir, mask, out1);
}

// Round 8
// 589.719 us; speedup vs baseline: 5.6877x; 5.6877x over previous
//
#include <hip/hip_runtime.h>
#include <hip/hip_bf16.h>

typedef unsigned int u32;
typedef unsigned short u16;
typedef __attribute__((ext_vector_type(8))) short short8v;
typedef __attribute__((ext_vector_type(4))) float f32x4;

#define BB 512
#define NN 256
#define DD 128
#define SCALE 0.08838834764831845f

__device__ __forceinline__ float bf2f(u16 u) {
  union { u32 i; float f; } v; v.i = ((u32)u) << 16; return v.f;
}
__device__ __forceinline__ u16 f2bf(float f) {
  union { u32 i; float f; } v; v.f = f;
  u32 i = v.i;
  u32 rounded = i + 0x7FFFu + ((i >> 16) & 1u);
  return (u16)(rounded >> 16);
}
__device__ __forceinline__ u32 pack2(float a, float b) {
  return (u32)f2bf(a) | ((u32)f2bf(b) << 16);
}

// XOR-swizzled byte offsets (T2/G4): spreads 16 consecutive rows over 8 16B slots.
#define SWZ(row, byteInRow)  ((((row) * 256) + (byteInRow)) ^ (((row) & 7) << 4))  // 256B rows
#define SWZT(row, byteInRow) ((((row) * 512) + (byteInRow)) ^ (((row) & 7) << 4))  // 512B rows

// ---------------- K0: M1T/M2T = Wq^T Wk  (stored as M[dp*128+d] = M?[d][dp]) ----
__global__ void k_prep(const float* __restrict__ Wq1, const float* __restrict__ Wk1,
                       const float* __restrict__ Wq2, const float* __restrict__ Wk2,
                       float* __restrict__ M) {
  int dp = blockIdx.x & 127;
  bool first = blockIdx.x < 128;
  const float* Wq = first ? Wq1 : Wq2;
  const float* Wk = first ? Wk1 : Wk2;
  float* out = M + (first ? 0 : 16384);
  int d = threadIdx.x;
  float acc = 0.f;
  for (int e = 0; e < 128; ++e)
    acc += Wq[e * 128 + d] * Wk[e * 128 + dp];
  out[dp * 128 + d] = acc;  // M?[d][dp]
}

// ---------------- K1: stage 1 (alpha, sat_out) + k2 projection (UNCHANGED, verified) ----
__global__ __launch_bounds__(512) void k_stage1(
    const float* __restrict__ mir, const float* __restrict__ sat,
    const float* __restrict__ M, float* __restrict__ out0, float* __restrict__ out1) {
  extern __shared__ char smem[];
  u16* m1b = (u16*)smem;               // [128][128] bf16: m1b[dp*128+d] = M1[d][dp]
  u16* m2b = m1b + 16384;              // [128][128]
  float* mirS = (float*)(m2b + 16384); // [16][128]
  int tid = threadIdx.x;
  for (int idx = tid; idx < 16384; idx += 512) {
    m1b[idx] = f2bf(M[idx]);
    m2b[idx] = f2bf(M[16384 + idx]);
  }
  int lane = tid & 63;
  int w = tid >> 6;
  int n0 = w, n1 = w + 8;
  size_t base = (size_t)blockIdx.x * 256;
  const u32* m1w = (const u32*)m1b;
  const u32* m2w = (const u32*)m2b;
  for (int it = 0; it < 16; ++it) {
    size_t nb = base + (size_t)it * 16;
    __syncthreads();
    for (int idx = tid; idx < 2048; idx += 512)
      mirS[idx] = mir[nb * 128 + idx];
    __syncthreads();
    float a00 = 0.f, a01 = 0.f, a10 = 0.f, a11 = 0.f;
    for (int dp = 0; dp < 128; ++dp) {
      u32 mu = m1w[dp * 64 + lane];
      float mv0 = bf2f((u16)mu), mv1 = bf2f((u16)(mu >> 16));
      float x0 = mirS[n0 * 128 + dp];
      float x1 = mirS[n1 * 128 + dp];
      a00 += mv0 * x0; a01 += mv1 * x0;
      a10 += mv0 * x1; a11 += mv1 * x1;
    }
    float2 sg0 = *(const float2*)(sat + (nb + n0) * 128 + 2 * lane);
    float2 sg1 = *(const float2*)(sat + (nb + n1) * 128 + 2 * lane);
    float p0 = sg0.x * a00 + sg0.y * a01;
    float p1 = sg1.x * a10 + sg1.y * a11;
    for (int o = 32; o; o >>= 1) {
      p0 += __shfl_xor(p0, o, 64);
      p1 += __shfl_xor(p1, o, 64);
    }
    float al0 = p0 * SCALE, al1 = p1 * SCALE;
    float mg0x = mirS[n0 * 128 + 2 * lane], mg0y = mirS[n0 * 128 + 2 * lane + 1];
    float mg1x = mirS[n1 * 128 + 2 * lane], mg1y = mirS[n1 * 128 + 2 * lane + 1];
    float so00 = sg0.x + al0 * (mg0x - sg0.x), so01 = sg0.y + al0 * (mg0y - sg0.y);
    float so10 = sg1.x + al1 * (mg1x - sg1.x), so11 = sg1.y + al1 * (mg1y - sg1.y);
    ((float2*)out0)[(nb + n0) * 64 + lane] = make_float2(so00, so01);
    ((float2*)out0)[(nb + n1) * 64 + lane] = make_float2(so10, so11);
    float b00 = 0.f, b01 = 0.f, b10 = 0.f, b11 = 0.f;
    for (int dph = 0; dph < 64; ++dph) {
      float xA0 = __shfl(so00, dph, 64);
      float xB0 = __shfl(so01, dph, 64);
      float xA1 = __shfl(so10, dph, 64);
      float xB1 = __shfl(so11, dph, 64);
      u32 muA = m2w[(2 * dph) * 64 + lane];
      u32 muB = m2w[(2 * dph + 1) * 64 + lane];
      float mA0 = bf2f((u16)muA), mA1 = bf2f((u16)(muA >> 16));
      float mB0 = bf2f((u16)muB), mB1 = bf2f((u16)(muB >> 16));
      b00 += mA0 * xA0 + mB0 * xB0;
      b01 += mA1 * xA0 + mB1 * xB0;
      b10 += mA0 * xA1 + mB0 * xB1;
      b11 += mA1 * xA1 + mB1 * xB1;
    }
    ((float2*)out1)[(nb + n0) * 64 + lane] = make_float2(b00, b01);
    ((float2*)out1)[(nb + n1) * 64 + lane] = make_float2(b10, b11);
  }
}

// ---------------- K2: MFMA attention. S^T = k2 @ mir^T; softmax over j; O = P @ mir.
// LDS: k2B [256][128]bf16 swz (64KB; becomes mirT [128][256] after QK)
//      mirB [256][128]bf16 swz (64KB; becomes per-wave P buffers after QK)
//      maskS int[256] (1KB). Total 132096 B -> 1 block/CU, 8 waves.
__global__ __launch_bounds__(512, 2) void k_attn(
    const float* __restrict__ mir, const int* __restrict__ mask,
    float* __restrict__ out1) {
  extern __shared__ char smem[];
  char* k2Bc = smem;            // 64KB
  char* mirBc = smem + 65536;   // 64KB
  int* maskS = (int*)(smem + 131072);

  int b = blockIdx.x, tid = threadIdx.x;
  int lane = tid & 63, w = tid >> 6;
  int rA = lane & 15;   // row-within-tile / C-column index
  int g = lane >> 4;    // k-group / C-row-group

  const float2* k2g = (const float2*)(out1 + (size_t)b * 32768);
  const float2* mirg = (const float2*)(mir + (size_t)b * 32768);
  // ---- stage k2B, mirB (bf16, swizzled), mask ----
  for (int idx = tid; idx < 16384; idx += 512) {
    int j = idx >> 6, c = idx & 63;  // c = d-pair
    float2 kf = k2g[idx];
    *(u32*)(k2Bc + SWZ(j, c * 4)) = pack2(kf.x, kf.y);
    float2 mf = mirg[idx];
    *(u32*)(mirBc + SWZ(j, c * 4)) = pack2(mf.x, mf.y);
  }
  if (tid < 256) maskS[tid] = mask[b * 256 + tid];
  __syncthreads();

  // ---- QK: S^T[j][i] = sum_d k2[j][d] * mir[i][d]; wave w owns i in [32w, 32w+32) ----
  f32x4 acc[16][2];
#pragma unroll
  for (int jt = 0; jt < 16; ++jt)
#pragma unroll
    for (int it = 0; it < 2; ++it) acc[jt][it] = (f32x4)(0.f);
#pragma unroll
  for (int kk = 0; kk < 4; ++kk) {
    int kb = (kk * 32 + g * 8) * 2;  // byte offset of k-chunk within a row
    short8v bfr[2];
#pragma unroll
    for (int it = 0; it < 2; ++it)
      bfr[it] = *(const short8v*)(mirBc + SWZ(32 * w + it * 16 + rA, kb));
#pragma unroll
    for (int jt = 0; jt < 16; ++jt) {
      short8v afr = *(const short8v*)(k2Bc + SWZ(jt * 16 + rA, kb));
#pragma unroll
      for (int it = 0; it < 2; ++it)
        acc[jt][it] = __builtin_amdgcn_mfma_f32_16x16x32_bf16(afr, bfr[it], acc[jt][it], 0, 0, 0);
    }
  }
  __syncthreads();  // all QK LDS reads done; k2B/mirB regions now dead

  // ---- re-stage mirT [d][j] (j-fast) into k2B region from global (L2-hot) ----
  {
    const float* mirf = mir + (size_t)b * 32768;
    int d = tid & 127, jb = tid >> 7;  // jb in [0,4)
    for (int i2 = 0; i2 < 32; ++i2) {
      int j2 = jb + 4 * i2;  // [0,128): j-pair index
      float a0 = mirf[(size_t)(2 * j2) * 128 + d];
      float a1 = mirf[(size_t)(2 * j2 + 1) * 128 + d];
      *(u32*)(k2Bc + SWZT(d, j2 * 4)) = pack2(a0, a1);
    }
  }

  // ---- softmax over j (C-layout: j = jt*16 + g*4 + r; i = 32w + it*16 + rA) ----
#pragma unroll
  for (int it = 0; it < 2; ++it) {
    float mx = -1e30f;
#pragma unroll
    for (int jt = 0; jt < 16; ++jt)
#pragma unroll
      for (int r = 0; r < 4; ++r) {
        int j = jt * 16 + g * 4 + r;
        float s = maskS[j] ? acc[jt][it][r] * SCALE : -1e30f;
        acc[jt][it][r] = s;
        mx = fmaxf(mx, s);
      }
    mx = fmaxf(mx, __shfl_xor(mx, 16, 64));
    mx = fmaxf(mx, __shfl_xor(mx, 32, 64));
    float sum = 0.f;
#pragma unroll
    for (int jt = 0; jt < 16; ++jt)
#pragma unroll
      for (int r = 0; r < 4; ++r) {
        float e = __expf(acc[jt][it][r] - mx);
        acc[jt][it][r] = e;
        sum += e;
      }
    sum += __shfl_xor(sum, 16, 64);
    sum += __shfl_xor(sum, 32, 64);
    float inv = 1.f / sum;
#pragma unroll
    for (int jt = 0; jt < 16; ++jt)
#pragma unroll
      for (int r = 0; r < 4; ++r) acc[jt][it][r] *= inv;
  }
  __syncthreads();  // mirT fully staged before PV B-reads

  // ---- PV: O[i][d] = sum_j P[i][j] * mir[j][d], two j-halves through per-wave P LDS ----
  char* Pw = mirBc + w * 8192;  // per-wave [32][128] bf16, swizzled 256B rows
  f32x4 oacc[2][8];
#pragma unroll
  for (int it = 0; it < 2; ++it)
#pragma unroll
    for (int dt = 0; dt < 8; ++dt) oacc[it][dt] = (f32x4)(0.f);

  for (int h = 0; h < 2; ++h) {
    // write normalized P half (bf16) from C-layout regs
#pragma unroll
    for (int it = 0; it < 2; ++it)
#pragma unroll
      for (int jt8 = 0; jt8 < 8; ++jt8) {
        int jt = 8 * h + jt8;
#pragma unroll
        for (int r = 0; r < 4; ++r) {
          int iLoc = it * 16 + rA;
          int jh = jt8 * 16 + g * 4 + r;
          *(u16*)(Pw + SWZ(iLoc, jh * 2)) = f2bf(acc[jt][it][r]);
        }
      }
    // MFMA: A = P rows (own), B = mirT rows (shared, read-only)
#pragma unroll
    for (int kk2 = 0; kk2 < 4; ++kk2) {
      int kbP = (kk2 * 32 + g * 8) * 2;           // j-offset within P row (half-local)
      int kbT = (128 * h + kk2 * 32 + g * 8) * 2; // j-offset within mirT row (global)
      short8v pa[2];
#pragma unroll
      for (int it = 0; it < 2; ++it)
        pa[it] = *(const short8v*)(Pw + SWZ(it * 16 + rA, kbP));
#pragma unroll
      for (int dt = 0; dt < 8; ++dt) {
        short8v vb = *(const short8v*)(k2Bc + SWZT(dt * 16 + rA, kbT));
#pragma unroll
        for (int it = 0; it < 2; ++it)
          oacc[it][dt] = __builtin_amdgcn_mfma_f32_16x16x32_bf16(pa[it], vb, oacc[it][dt], 0, 0, 0);
      }
    }
  }

  // ---- write O (fp32): C-layout col d = dt*16 + rA, row i = 32w + it*16 + g*4 + r ----
#pragma unroll
  for (int it = 0; it < 2; ++it)
#pragma unroll
    for (int dt = 0; dt < 8; ++dt)
#pragma unroll
      for (int r = 0; r < 4; ++r) {
        int iG = 32 * w + it * 16 + g * 4 + r;
        int dG = dt * 16 + rA;
        out1[((size_t)b * 256 + iG) * 128 + dG] = oacc[it][dt][r];
      }
}

extern "C" void kernel_launch(void* const* d_in, const int* in_sizes, int n_in,
                              void* d_out, int out_size, void* d_ws, size_t ws_size,
                              hipStream_t stream) {
  const float* mir = (const float*)d_in[0];
  const float* sat = (const float*)d_in[1];
  const int* mask = (const int*)d_in[2];
  const float* Wq1 = (const float*)d_in[3];
  const float* Wk1 = (const float*)d_in[4];
  const float* Wq2 = (const float*)d_in[5];
  const float* Wk2 = (const float*)d_in[6];
  float* out0 = (float*)d_out;
  float* out1 = out0 + (size_t)BB * NN * DD;
  float* M = (float*)d_ws;

  hipFuncSetAttribute((const void*)k_stage1, hipFuncAttributeMaxDynamicSharedMemorySize, 73728);
  hipFuncSetAttribute((const void*)k_attn, hipFuncAttributeMaxDynamicSharedMemorySize, 132096);

  k_prep<<<256, 128, 0, stream>>>(Wq1, Wk1, Wq2, Wk2, M);
  k_stage1<<<512, 512, 73728, stream>>>(mir, sat, M, out0, out1);
  k_attn<<<512, 512, 132096, stream>>>(mir, mask, out1);
}

// Round 9
// 351.210 us; speedup vs baseline: 9.5502x; 1.6791x over previous
//
#include <hip/hip_runtime.h>
#include <hip/hip_bf16.h>

typedef unsigned int u32;
typedef unsigned short u16;
typedef __attribute__((ext_vector_type(8))) short short8v;
typedef __attribute__((ext_vector_type(4))) float f32x4;

#define BB 512
#define NN 256
#define DD 128
#define SCALE 0.08838834764831845f

__device__ __forceinline__ float bf2f(u16 u) {
  union { u32 i; float f; } v; v.i = ((u32)u) << 16; return v.f;
}
__device__ __forceinline__ u16 f2bf(float f) {
  union { u32 i; float f; } v; v.f = f;
  u32 i = v.i;
  u32 rounded = i + 0x7FFFu + ((i >> 16) & 1u);
  return (u16)(rounded >> 16);
}
__device__ __forceinline__ u32 pack2(float a, float b) {
  return (u32)f2bf(a) | ((u32)f2bf(b) << 16);
}

// XOR-swizzled byte offsets (T2/G4): spreads 16 consecutive rows over 8 16B slots.
#define SWZ(row, byteInRow)  ((((row) * 256) + (byteInRow)) ^ (((row) & 7) << 4))  // 256B rows
#define SWZT(row, byteInRow) ((((row) * 512) + (byteInRow)) ^ (((row) & 7) << 4))  // 512B rows

// ---------------- K0: M1/M2 = Wq^T Wk, stored BF16 row-major by output dim:
// Mbf[d*128+dp] = M?[d][dp], ready for 16B B-fragment loads.
__global__ void k_prep(const float* __restrict__ Wq1, const float* __restrict__ Wk1,
                       const float* __restrict__ Wq2, const float* __restrict__ Wk2,
                       u16* __restrict__ Mbf) {
  int d = blockIdx.x & 127;
  bool first = blockIdx.x < 128;
  const float* Wq = first ? Wq1 : Wq2;
  const float* Wk = first ? Wk1 : Wk2;
  u16* out = Mbf + (first ? 0 : 16384);
  int dp = threadIdx.x;
  float acc = 0.f;
  for (int e = 0; e < 128; ++e)
    acc += Wq[e * 128 + d] * Wk[e * 128 + dp];
  out[d * 128 + dp] = f2bf(acc);
}

// ---------------- K1: MFMA stage 1. Per wave: 16 rows. Barrier-free.
// GEMM1: t1 = mir @ M1^T (MFMA, A=mir global-direct, B=M1bf global-direct)
// alpha = rowdot(t1, sat)*scale (C-layout regs + shfl_xor over 16-lane col group)
// sat_out -> out0 (fp32) and per-wave LDS (bf16, swizzled) for GEMM2 A-frags
// GEMM2: k2 = sat_out @ M2^T -> out1 (fp32)
__global__ __launch_bounds__(512, 2) void k_stage1(
    const float* __restrict__ mir, const float* __restrict__ sat,
    const u16* __restrict__ Mbf, float* __restrict__ out0, float* __restrict__ out1) {
  __shared__ char soB[32768];  // 8 waves x [16][128] bf16, swizzled 256B rows
  int tid = threadIdx.x;
  int lane = tid & 63, w = tid >> 6;
  int rA = lane & 15;  // A/B-frag row index; C col index
  int g = lane >> 4;   // k-group; C row group
  int base = blockIdx.x * 128 + w * 16;
  const u16* M1bf = Mbf;
  const u16* M2bf = Mbf + 16384;
  char* wbuf = soB + w * 4096;

  // ---- A-frags: mir rows (lane rA -> row base+rA, k-slice g*8 + kk*32) ----
  short8v amir[4];
#pragma unroll
  for (int kk = 0; kk < 4; ++kk) {
    const float* p = mir + (size_t)(base + rA) * 128 + kk * 32 + g * 8;
    float4 f0 = *(const float4*)p;
    float4 f1 = *(const float4*)(p + 4);
    union { short8v s; u32 u[4]; } uu;
    uu.u[0] = pack2(f0.x, f0.y); uu.u[1] = pack2(f0.z, f0.w);
    uu.u[2] = pack2(f1.x, f1.y); uu.u[3] = pack2(f1.z, f1.w);
    amir[kk] = uu.s;
  }
  // ---- GEMM1: acc1[et] = C1[n=g*4+r][d=et*16+rA] ----
  f32x4 acc1[8];
#pragma unroll
  for (int et = 0; et < 8; ++et) {
    acc1[et] = (f32x4)(0.f);
#pragma unroll
    for (int kk = 0; kk < 4; ++kk) {
      short8v bf = *(const short8v*)(M1bf + (et * 16 + rA) * 128 + kk * 32 + g * 8);
      acc1[et] = __builtin_amdgcn_mfma_f32_16x16x32_bf16(amir[kk], bf, acc1[et], 0, 0, 0);
    }
  }
  // ---- load sat/mir at C-layout positions ----
  float sval[8][4], mval[8][4];
#pragma unroll
  for (int r = 0; r < 4; ++r) {
    size_t n = (size_t)base + g * 4 + r;
#pragma unroll
    for (int et = 0; et < 8; ++et) {
      sval[et][r] = sat[n * 128 + et * 16 + rA];
      mval[et][r] = mir[n * 128 + et * 16 + rA];
    }
  }
  // ---- alpha[n] = scale * sum_d t1[n][d]*sat[n][d]; reduce over rA lanes ----
  float alph[4];
#pragma unroll
  for (int r = 0; r < 4; ++r) {
    float p = 0.f;
#pragma unroll
    for (int et = 0; et < 8; ++et) p += acc1[et][r] * sval[et][r];
    p += __shfl_xor(p, 1, 64);
    p += __shfl_xor(p, 2, 64);
    p += __shfl_xor(p, 4, 64);
    p += __shfl_xor(p, 8, 64);
    alph[r] = p * SCALE;
  }
  // ---- sat_out: write out0 fp32 + wave-private LDS bf16 (A-layout transpose) ----
#pragma unroll
  for (int r = 0; r < 4; ++r) {
    size_t n = (size_t)base + g * 4 + r;
#pragma unroll
    for (int et = 0; et < 8; ++et) {
      float so = sval[et][r] + alph[r] * (mval[et][r] - sval[et][r]);
      out0[n * 128 + et * 16 + rA] = so;
      *(u16*)(wbuf + SWZ(g * 4 + r, (et * 16 + rA) * 2)) = f2bf(so);
    }
  }
  // ---- GEMM2: k2 = sat_out @ M2^T ----
  short8v aso[4];
#pragma unroll
  for (int kk = 0; kk < 4; ++kk)
    aso[kk] = *(const short8v*)(wbuf + SWZ(rA, kk * 64 + g * 16));
  f32x4 acc2[8];
#pragma unroll
  for (int et = 0; et < 8; ++et) {
    acc2[et] = (f32x4)(0.f);
#pragma unroll
    for (int kk = 0; kk < 4; ++kk) {
      short8v bf = *(const short8v*)(M2bf + (et * 16 + rA) * 128 + kk * 32 + g * 8);
      acc2[et] = __builtin_amdgcn_mfma_f32_16x16x32_bf16(aso[kk], bf, acc2[et], 0, 0, 0);
    }
  }
#pragma unroll
  for (int r = 0; r < 4; ++r) {
    size_t n = (size_t)base + g * 4 + r;
#pragma unroll
    for (int et = 0; et < 8; ++et)
      out1[n * 128 + et * 16 + rA] = acc2[et][r];
  }
}

// ---------------- K2: MFMA attention (UNCHANGED from round-8 verified version) ----
__global__ __launch_bounds__(512, 2) void k_attn(
    const float* __restrict__ mir, const int* __restrict__ mask,
    float* __restrict__ out1) {
  extern __shared__ char smem[];
  char* k2Bc = smem;            // 64KB
  char* mirBc = smem + 65536;   // 64KB
  int* maskS = (int*)(smem + 131072);

  int b = blockIdx.x, tid = threadIdx.x;
  int lane = tid & 63, w = tid >> 6;
  int rA = lane & 15;   // row-within-tile / C-column index
  int g = lane >> 4;    // k-group / C-row-group

  const float2* k2g = (const float2*)(out1 + (size_t)b * 32768);
  const float2* mirg = (const float2*)(mir + (size_t)b * 32768);
  // ---- stage k2B, mirB (bf16, swizzled), mask ----
  for (int idx = tid; idx < 16384; idx += 512) {
    int j = idx >> 6, c = idx & 63;  // c = d-pair
    float2 kf = k2g[idx];
    *(u32*)(k2Bc + SWZ(j, c * 4)) = pack2(kf.x, kf.y);
    float2 mf = mirg[idx];
    *(u32*)(mirBc + SWZ(j, c * 4)) = pack2(mf.x, mf.y);
  }
  if (tid < 256) maskS[tid] = mask[b * 256 + tid];
  __syncthreads();

  // ---- QK: S^T[j][i] = sum_d k2[j][d] * mir[i][d]; wave w owns i in [32w, 32w+32) ----
  f32x4 acc[16][2];
#pragma unroll
  for (int jt = 0; jt < 16; ++jt)
#pragma unroll
    for (int it = 0; it < 2; ++it) acc[jt][it] = (f32x4)(0.f);
#pragma unroll
  for (int kk = 0; kk < 4; ++kk) {
    int kb = (kk * 32 + g * 8) * 2;  // byte offset of k-chunk within a row
    short8v bfr[2];
#pragma unroll
    for (int it = 0; it < 2; ++it)
      bfr[it] = *(const short8v*)(mirBc + SWZ(32 * w + it * 16 + rA, kb));
#pragma unroll
    for (int jt = 0; jt < 16; ++jt) {
      short8v afr = *(const short8v*)(k2Bc + SWZ(jt * 16 + rA, kb));
#pragma unroll
      for (int it = 0; it < 2; ++it)
        acc[jt][it] = __builtin_amdgcn_mfma_f32_16x16x32_bf16(afr, bfr[it], acc[jt][it], 0, 0, 0);
    }
  }
  __syncthreads();  // all QK LDS reads done; k2B/mirB regions now dead

  // ---- re-stage mirT [d][j] (j-fast) into k2B region from global (L2-hot) ----
  {
    const float* mirf = mir + (size_t)b * 32768;
    int d = tid & 127, jb = tid >> 7;  // jb in [0,4)
    for (int i2 = 0; i2 < 32; ++i2) {
      int j2 = jb + 4 * i2;  // [0,128): j-pair index
      float a0 = mirf[(size_t)(2 * j2) * 128 + d];
      float a1 = mirf[(size_t)(2 * j2 + 1) * 128 + d];
      *(u32*)(k2Bc + SWZT(d, j2 * 4)) = pack2(a0, a1);
    }
  }

  // ---- softmax over j (C-layout: j = jt*16 + g*4 + r; i = 32w + it*16 + rA) ----
#pragma unroll
  for (int it = 0; it < 2; ++it) {
    float mx = -1e30f;
#pragma unroll
    for (int jt = 0; jt < 16; ++jt)
#pragma unroll
      for (int r = 0; r < 4; ++r) {
        int j = jt * 16 + g * 4 + r;
        float s = maskS[j] ? acc[jt][it][r] * SCALE : -1e30f;
        acc[jt][it][r] = s;
        mx = fmaxf(mx, s);
      }
    mx = fmaxf(mx, __shfl_xor(mx, 16, 64));
    mx = fmaxf(mx, __shfl_xor(mx, 32, 64));
    float sum = 0.f;
#pragma unroll
    for (int jt = 0; jt < 16; ++jt)
#pragma unroll
      for (int r = 0; r < 4; ++r) {
        float e = __expf(acc[jt][it][r] - mx);
        acc[jt][it][r] = e;
        sum += e;
      }
    sum += __shfl_xor(sum, 16, 64);
    sum += __shfl_xor(sum, 32, 64);
    float inv = 1.f / sum;
#pragma unroll
    for (int jt = 0; jt < 16; ++jt)
#pragma unroll
      for (int r = 0; r < 4; ++r) acc[jt][it][r] *= inv;
  }
  __syncthreads();  // mirT fully staged before PV B-reads

  // ---- PV: O[i][d] = sum_j P[i][j] * mir[j][d], two j-halves through per-wave P LDS ----
  char* Pw = mirBc + w * 8192;  // per-wave [32][128] bf16, swizzled 256B rows
  f32x4 oacc[2][8];
#pragma unroll
  for (int it = 0; it < 2; ++it)
#pragma unroll
    for (int dt = 0; dt < 8; ++dt) oacc[it][dt] = (f32x4)(0.f);

  for (int h = 0; h < 2; ++h) {
    // write normalized P half (bf16) from C-layout regs
#pragma unroll
    for (int it = 0; it < 2; ++it)
#pragma unroll
      for (int jt8 = 0; jt8 < 8; ++jt8) {
        int jt = 8 * h + jt8;
#pragma unroll
        for (int r = 0; r < 4; ++r) {
          int iLoc = it * 16 + rA;
          int jh = jt8 * 16 + g * 4 + r;
          *(u16*)(Pw + SWZ(iLoc, jh * 2)) = f2bf(acc[jt][it][r]);
        }
      }
    // MFMA: A = P rows (own), B = mirT rows (shared, read-only)
#pragma unroll
    for (int kk2 = 0; kk2 < 4; ++kk2) {
      int kbP = (kk2 * 32 + g * 8) * 2;           // j-offset within P row (half-local)
      int kbT = (128 * h + kk2 * 32 + g * 8) * 2; // j-offset within mirT row (global)
      short8v pa[2];
#pragma unroll
      for (int it = 0; it < 2; ++it)
        pa[it] = *(const short8v*)(Pw + SWZ(it * 16 + rA, kbP));
#pragma unroll
      for (int dt = 0; dt < 8; ++dt) {
        short8v vb = *(const short8v*)(k2Bc + SWZT(dt * 16 + rA, kbT));
#pragma unroll
        for (int it = 0; it < 2; ++it)
          oacc[it][dt] = __builtin_amdgcn_mfma_f32_16x16x32_bf16(pa[it], vb, oacc[it][dt], 0, 0, 0);
      }
    }
  }

  // ---- write O (fp32): C-layout col d = dt*16 + rA, row i = 32w + it*16 + g*4 + r ----
#pragma unroll
  for (int it = 0; it < 2; ++it)
#pragma unroll
    for (int dt = 0; dt < 8; ++dt)
#pragma unroll
      for (int r = 0; r < 4; ++r) {
        int iG = 32 * w + it * 16 + g * 4 + r;
        int dG = dt * 16 + rA;
        out1[((size_t)b * 256 + iG) * 128 + dG] = oacc[it][dt][r];
      }
}

extern "C" void kernel_launch(void* const* d_in, const int* in_sizes, int n_in,
                              void* d_out, int out_size, void* d_ws, size_t ws_size,
                              hipStream_t stream) {
  const float* mir = (const float*)d_in[0];
  const float* sat = (const float*)d_in[1];
  const int* mask = (const int*)d_in[2];
  const float* Wq1 = (const float*)d_in[3];
  const float* Wk1 = (const float*)d_in[4];
  const float* Wq2 = (const float*)d_in[5];
  const float* Wk2 = (const float*)d_in[6];
  float* out0 = (float*)d_out;
  float* out1 = out0 + (size_t)BB * NN * DD;
  u16* Mbf = (u16*)d_ws;  // M1 bf16 [128][128] then M2 bf16 [128][128]

  hipFuncSetAttribute((const void*)k_attn, hipFuncAttributeMaxDynamicSharedMemorySize, 132096);

  k_prep<<<256, 128, 0, stream>>>(Wq1, Wk1, Wq2, Wk2, Mbf);
  k_stage1<<<1024, 512, 0, stream>>>(mir, sat, Mbf, out0, out1);
  k_attn<<<512, 512, 132096, stream>>>(mir, mask, out1);
}

// Round 10
// 322.658 us; speedup vs baseline: 10.3953x; 1.0885x over previous
//
#include <hip/hip_runtime.h>
#include <hip/hip_bf16.h>

typedef unsigned int u32;
typedef unsigned short u16;
typedef __attribute__((ext_vector_type(8))) short short8v;
typedef __attribute__((ext_vector_type(4))) float f32x4;

#define BB 512
#define NN 256
#define DD 128
#define SCALE 0.08838834764831845f

__device__ __forceinline__ float bf2f(u16 u) {
  union { u32 i; float f; } v; v.i = ((u32)u) << 16; return v.f;
}
__device__ __forceinline__ u16 f2bf(float f) {
  union { u32 i; float f; } v; v.f = f;
  u32 i = v.i;
  u32 rounded = i + 0x7FFFu + ((i >> 16) & 1u);
  return (u16)(rounded >> 16);
}
__device__ __forceinline__ u32 pack2(float a, float b) {
  return (u32)f2bf(a) | ((u32)f2bf(b) << 16);
}

// XOR-swizzled byte offsets (T2/G4): spreads 16 consecutive rows over 8 16B slots.
#define SWZ(row, byteInRow)  ((((row) * 256) + (byteInRow)) ^ (((row) & 7) << 4))  // 256B rows
#define SWZT(row, byteInRow) ((((row) * 512) + (byteInRow)) ^ (((row) & 7) << 4))  // 512B rows

// ---------------- K0: M1/M2 = Wq^T Wk, stored BF16 row-major by output dim:
// Mbf[d*128+dp] = M?[d][dp], ready for 16B B-fragment loads.
__global__ void k_prep(const float* __restrict__ Wq1, const float* __restrict__ Wk1,
                       const float* __restrict__ Wq2, const float* __restrict__ Wk2,
                       u16* __restrict__ Mbf) {
  int d = blockIdx.x & 127;
  bool first = blockIdx.x < 128;
  const float* Wq = first ? Wq1 : Wq2;
  const float* Wk = first ? Wk1 : Wk2;
  u16* out = Mbf + (first ? 0 : 16384);
  int dp = threadIdx.x;
  float acc = 0.f;
  for (int e = 0; e < 128; ++e)
    acc += Wq[e * 128 + d] * Wk[e * 128 + dp];
  out[d * 128 + dp] = f2bf(acc);
}

// ---------------- K1 (fused): stage1 + attention, one block per batch.
// reg0 (64KB): sat_out -> k2 (in place) -> mirT.  reg1 (64KB): mir -> per-wave P.
// maskS: int[256]. Total 132096 B -> 1 block/CU, 8 waves.
__global__ __launch_bounds__(512, 2) void k_fused(
    const float* __restrict__ mir, const float* __restrict__ sat,
    const int* __restrict__ mask, const u16* __restrict__ Mbf,
    float* __restrict__ out0, float* __restrict__ out1) {
  extern __shared__ char smem[];
  char* reg0 = smem;            // sat_out -> k2 -> mirT
  char* reg1 = smem + 65536;    // mir -> P buffers
  int* maskS = (int*)(smem + 131072);

  int b = blockIdx.x, tid = threadIdx.x;
  int lane = tid & 63, w = tid >> 6;
  int rA = lane & 15;   // frag row index; C col index
  int g = lane >> 4;    // k-group; C row group
  const u16* M1bf = Mbf;
  const u16* M2bf = Mbf + 16384;

  // ---- stage mir (bf16, swizzled) + mask ----
  const float2* mirg = (const float2*)(mir + (size_t)b * 32768);
  for (int idx = tid; idx < 16384; idx += 512) {
    int j = idx >> 6, c = idx & 63;  // c = d-pair
    float2 mf = mirg[idx];
    *(u32*)(reg1 + SWZ(j, c * 4)) = pack2(mf.x, mf.y);
  }
  if (tid < 256) maskS[tid] = mask[b * 256 + tid];
  __syncthreads();

  // ---- GEMM1: t1 = mir @ M1^T for this wave's 32 rows ----
  f32x4 acc1[2][8];
#pragma unroll
  for (int it = 0; it < 2; ++it)
#pragma unroll
    for (int et = 0; et < 8; ++et) acc1[it][et] = (f32x4)(0.f);
#pragma unroll
  for (int kk = 0; kk < 4; ++kk) {
    int kb = (kk * 32 + g * 8) * 2;
    short8v am[2];
#pragma unroll
    for (int it = 0; it < 2; ++it)
      am[it] = *(const short8v*)(reg1 + SWZ(32 * w + it * 16 + rA, kb));
#pragma unroll
    for (int et = 0; et < 8; ++et) {
      short8v bf = *(const short8v*)(M1bf + (et * 16 + rA) * 128 + kk * 32 + g * 8);
#pragma unroll
      for (int it = 0; it < 2; ++it)
        acc1[it][et] = __builtin_amdgcn_mfma_f32_16x16x32_bf16(am[it], bf, acc1[it][et], 0, 0, 0);
    }
  }

  // ---- alpha + sat_out (out0 + reg0 bf16), per it-half to bound registers ----
  size_t gbase = (size_t)b * 256 + 32 * w;
#pragma unroll
  for (int it = 0; it < 2; ++it) {
    float sv[8][4], mv[8][4];
#pragma unroll
    for (int r = 0; r < 4; ++r) {
      size_t n = gbase + it * 16 + g * 4 + r;
#pragma unroll
      for (int et = 0; et < 8; ++et) {
        sv[et][r] = sat[n * 128 + et * 16 + rA];
        mv[et][r] = mir[n * 128 + et * 16 + rA];
      }
    }
#pragma unroll
    for (int r = 0; r < 4; ++r) {
      float p = 0.f;
#pragma unroll
      for (int et = 0; et < 8; ++et) p += acc1[it][et][r] * sv[et][r];
      p += __shfl_xor(p, 1, 64);
      p += __shfl_xor(p, 2, 64);
      p += __shfl_xor(p, 4, 64);
      p += __shfl_xor(p, 8, 64);
      float al = p * SCALE;
      size_t n = gbase + it * 16 + g * 4 + r;
      int jloc = 32 * w + it * 16 + g * 4 + r;
#pragma unroll
      for (int et = 0; et < 8; ++et) {
        float so = sv[et][r] + al * (mv[et][r] - sv[et][r]);
        out0[n * 128 + et * 16 + rA] = so;
        *(u16*)(reg0 + SWZ(jloc, (et * 16 + rA) * 2)) = f2bf(so);
      }
    }
  }

  // ---- GEMM2: k2 = sat_out @ M2^T, in-place in reg0 (wave-private rows) ----
  short8v aso[2][4];
#pragma unroll
  for (int it = 0; it < 2; ++it)
#pragma unroll
    for (int kk = 0; kk < 4; ++kk)
      aso[it][kk] = *(const short8v*)(reg0 + SWZ(32 * w + it * 16 + rA, (kk * 32 + g * 8) * 2));
  f32x4 acc2[2][8];
#pragma unroll
  for (int it = 0; it < 2; ++it)
#pragma unroll
    for (int et = 0; et < 8; ++et) acc2[it][et] = (f32x4)(0.f);
#pragma unroll
  for (int kk = 0; kk < 4; ++kk) {
#pragma unroll
    for (int et = 0; et < 8; ++et) {
      short8v bf = *(const short8v*)(M2bf + (et * 16 + rA) * 128 + kk * 32 + g * 8);
#pragma unroll
      for (int it = 0; it < 2; ++it)
        acc2[it][et] = __builtin_amdgcn_mfma_f32_16x16x32_bf16(aso[it][kk], bf, acc2[it][et], 0, 0, 0);
    }
  }
#pragma unroll
  for (int it = 0; it < 2; ++it)
#pragma unroll
    for (int r = 0; r < 4; ++r) {
      int jloc = 32 * w + it * 16 + g * 4 + r;
#pragma unroll
      for (int et = 0; et < 8; ++et)
        *(u16*)(reg0 + SWZ(jloc, (et * 16 + rA) * 2)) = f2bf(acc2[it][et][r]);
    }
  __syncthreads();  // k2 complete block-wide; mir reads by GEMM1 all done

  // ---- QK: S^T[j][i] = sum_d k2[j][d] * mir[i][d] (verbatim r8-verified) ----
  f32x4 acc[16][2];
#pragma unroll
  for (int jt = 0; jt < 16; ++jt)
#pragma unroll
    for (int it = 0; it < 2; ++it) acc[jt][it] = (f32x4)(0.f);
#pragma unroll
  for (int kk = 0; kk < 4; ++kk) {
    int kb = (kk * 32 + g * 8) * 2;
    short8v bfr[2];
#pragma unroll
    for (int it = 0; it < 2; ++it)
      bfr[it] = *(const short8v*)(reg1 + SWZ(32 * w + it * 16 + rA, kb));
#pragma unroll
    for (int jt = 0; jt < 16; ++jt) {
      short8v afr = *(const short8v*)(reg0 + SWZ(jt * 16 + rA, kb));
#pragma unroll
      for (int it = 0; it < 2; ++it)
        acc[jt][it] = __builtin_amdgcn_mfma_f32_16x16x32_bf16(afr, bfr[it], acc[jt][it], 0, 0, 0);
    }
  }
  __syncthreads();  // all QK LDS reads done; reg0/reg1 contents now dead

  // ---- re-stage mirT [d][j] (j-fast) into reg0 from global (L2-hot) ----
  {
    const float* mirf = mir + (size_t)b * 32768;
    int d = tid & 127, jb = tid >> 7;  // jb in [0,4)
    for (int i2 = 0; i2 < 32; ++i2) {
      int j2 = jb + 4 * i2;  // [0,128): j-pair index
      float a0 = mirf[(size_t)(2 * j2) * 128 + d];
      float a1 = mirf[(size_t)(2 * j2 + 1) * 128 + d];
      *(u32*)(reg0 + SWZT(d, j2 * 4)) = pack2(a0, a1);
    }
  }

  // ---- softmax over j (verbatim r8-verified) ----
#pragma unroll
  for (int it = 0; it < 2; ++it) {
    float mx = -1e30f;
#pragma unroll
    for (int jt = 0; jt < 16; ++jt)
#pragma unroll
      for (int r = 0; r < 4; ++r) {
        int j = jt * 16 + g * 4 + r;
        float s = maskS[j] ? acc[jt][it][r] * SCALE : -1e30f;
        acc[jt][it][r] = s;
        mx = fmaxf(mx, s);
      }
    mx = fmaxf(mx, __shfl_xor(mx, 16, 64));
    mx = fmaxf(mx, __shfl_xor(mx, 32, 64));
    float sum = 0.f;
#pragma unroll
    for (int jt = 0; jt < 16; ++jt)
#pragma unroll
      for (int r = 0; r < 4; ++r) {
        float e = __expf(acc[jt][it][r] - mx);
        acc[jt][it][r] = e;
        sum += e;
      }
    sum += __shfl_xor(sum, 16, 64);
    sum += __shfl_xor(sum, 32, 64);
    float inv = 1.f / sum;
#pragma unroll
    for (int jt = 0; jt < 16; ++jt)
#pragma unroll
      for (int r = 0; r < 4; ++r) acc[jt][it][r] *= inv;
  }
  __syncthreads();  // mirT fully staged before PV B-reads

  // ---- PV: O = P @ mir via two j-halves through per-wave P LDS (verbatim) ----
  char* Pw = reg1 + w * 8192;  // per-wave [32][128] bf16, swizzled 256B rows
  f32x4 oacc[2][8];
#pragma unroll
  for (int it = 0; it < 2; ++it)
#pragma unroll
    for (int dt = 0; dt < 8; ++dt) oacc[it][dt] = (f32x4)(0.f);

  for (int h = 0; h < 2; ++h) {
#pragma unroll
    for (int it = 0; it < 2; ++it)
#pragma unroll
      for (int jt8 = 0; jt8 < 8; ++jt8) {
        int jt = 8 * h + jt8;
#pragma unroll
        for (int r = 0; r < 4; ++r) {
          int iLoc = it * 16 + rA;
          int jh = jt8 * 16 + g * 4 + r;
          *(u16*)(Pw + SWZ(iLoc, jh * 2)) = f2bf(acc[jt][it][r]);
        }
      }
#pragma unroll
    for (int kk2 = 0; kk2 < 4; ++kk2) {
      int kbP = (kk2 * 32 + g * 8) * 2;
      int kbT = (128 * h + kk2 * 32 + g * 8) * 2;
      short8v pa[2];
#pragma unroll
      for (int it = 0; it < 2; ++it)
        pa[it] = *(const short8v*)(Pw + SWZ(it * 16 + rA, kbP));
#pragma unroll
      for (int dt = 0; dt < 8; ++dt) {
        short8v vb = *(const short8v*)(reg0 + SWZT(dt * 16 + rA, kbT));
#pragma unroll
        for (int it = 0; it < 2; ++it)
          oacc[it][dt] = __builtin_amdgcn_mfma_f32_16x16x32_bf16(pa[it], vb, oacc[it][dt], 0, 0, 0);
      }
    }
  }

  // ---- write O (fp32) ----
#pragma unroll
  for (int it = 0; it < 2; ++it)
#pragma unroll
    for (int dt = 0; dt < 8; ++dt)
#pragma unroll
      for (int r = 0; r < 4; ++r) {
        int iG = 32 * w + it * 16 + g * 4 + r;
        int dG = dt * 16 + rA;
        out1[((size_t)b * 256 + iG) * 128 + dG] = oacc[it][dt][r];
      }
}

extern "C" void kernel_launch(void* const* d_in, const int* in_sizes, int n_in,
                              void* d_out, int out_size, void* d_ws, size_t ws_size,
                              hipStream_t stream) {
  const float* mir = (const float*)d_in[0];
  const float* sat = (const float*)d_in[1];
  const int* mask = (const int*)d_in[2];
  const float* Wq1 = (const float*)d_in[3];
  const float* Wk1 = (const float*)d_in[4];
  const float* Wq2 = (const float*)d_in[5];
  const float* Wk2 = (const float*)d_in[6];
  float* out0 = (float*)d_out;
  float* out1 = out0 + (size_t)BB * NN * DD;
  u16* Mbf = (u16*)d_ws;  // M1 bf16 [128][128] then M2 bf16 [128][128]

  hipFuncSetAttribute((const void*)k_fused, hipFuncAttributeMaxDynamicSharedMemorySize, 132096);

  k_prep<<<256, 128, 0, stream>>>(Wq1, Wk1, Wq2, Wk2, Mbf);
  k_fused<<<512, 512, 132096, stream>>>(mir, sat, mask, Mbf, out0, out1);
}